// Round 5
// baseline (192.803 us; speedup 1.0000x reference)
//
#include <hip/hip_runtime.h>
#include <cstdint>
#include <cstddef>

#define N 4096
#define M 4096
#define DT 0.01f

#define BMT 128   // block rows (j)
#define BNT 256   // block cols (i)
#define BKT 32    // K elements per tile
#define TILEB 24576   // per-tile LDS: A 128x32 bf16 (8 KB) + B 256x32 bf16 (16 KB)
#define NBUF 6        // 6 tile buffers = 144 KB

typedef short bf16x8 __attribute__((ext_vector_type(8)));
typedef float f32x4 __attribute__((ext_vector_type(4)));

__device__ __forceinline__ unsigned short f2bf(float f) {
  unsigned u = __builtin_bit_cast(unsigned, f);
  return (unsigned short)((u + 0x7fffu + ((u >> 16) & 1u)) >> 16);  // RNE
}

// Fused prep. Blocks [0,4096): exp-transpose tiles -> kbT[i*N+l]=bf16(exp(-x[l*M+i])).
// Blocks [4096,8192): weighted Toeplitz row j: Tm[j*N+l] = w*h[j-l] (l<=j else 0),
// w = 1 + 0.5*[l==j] - 0.5*[l==0]   =>   out = fe[j] - dt*(Tm @ k)[j,i].
__global__ __launch_bounds__(256)
void prep_kernel(const float* __restrict__ x, const float* __restrict__ h,
                 unsigned short* __restrict__ kbT, unsigned short* __restrict__ Tm) {
  __shared__ __align__(16) unsigned short smem[64 * 66];  // 8448 B, both modes
  const int bid = (int)blockIdx.x;
  const int tid = threadIdx.x;

  if (bid < 4096) {
    // ---- exp-transpose 64x64 tile ----
    unsigned short (*tileT)[66] = (unsigned short(*)[66])smem;  // [i][l]
    const int i0 = (bid & 63) * 64, l0 = (bid >> 6) * 64;
    const int ci = (tid & 15) * 4;
    const int r0 = tid >> 4;
#pragma unroll
    for (int rr = 0; rr < 4; ++rr) {
      const int l = l0 + r0 + rr * 16;
      const float4 xv = *reinterpret_cast<const float4*>(&x[(size_t)l * M + i0 + ci]);
      const int lr = r0 + rr * 16;
      tileT[ci + 0][lr] = f2bf(__expf(-xv.x));
      tileT[ci + 1][lr] = f2bf(__expf(-xv.y));
      tileT[ci + 2][lr] = f2bf(__expf(-xv.z));
      tileT[ci + 3][lr] = f2bf(__expf(-xv.w));
    }
    __syncthreads();
    const int ir = tid >> 2, cc = tid & 3;
#pragma unroll
    for (int s = 0; s < 2; ++s) {
      const int ch = cc + s * 4;
      bf16x8 v = *reinterpret_cast<const bf16x8*>(&tileT[ir][ch * 8]);
      *reinterpret_cast<bf16x8*>(&kbT[(size_t)(i0 + ir) * N + l0 + ch * 8]) = v;
    }
  } else {
    // ---- Toeplitz row j ----
    const int j = bid - 4096;
    unsigned short* hb = smem;  // hb[0..4095] = bf16(h[.])
#pragma unroll
    for (int p = 0; p < 4; ++p) {
      const int idx = p * 1024 + tid * 4;
      const float4 hv = *reinterpret_cast<const float4*>(&h[idx]);
      ushort4 pk;
      pk.x = f2bf(hv.x); pk.y = f2bf(hv.y); pk.z = f2bf(hv.z); pk.w = f2bf(hv.w);
      *reinterpret_cast<ushort4*>(&hb[idx]) = pk;
    }
    __syncthreads();
    const int l0 = tid * 16;
    unsigned short v[16];
#pragma unroll
    for (int s = 0; s < 16; ++s) {
      const int l = l0 + s;
      unsigned short r = 0;
      if (l <= j) {
        const float w = 1.0f + (l == j ? 0.5f : 0.0f) - (l == 0 ? 0.5f : 0.0f);
        float hv = __builtin_bit_cast(float, (unsigned)hb[j - l] << 16);
        r = f2bf(w * hv);
      }
      v[s] = r;
    }
#pragma unroll
    for (int half = 0; half < 2; ++half) {
      uint4 pk;
      const unsigned short* q = &v[half * 8];
      pk.x = (unsigned)q[0] | ((unsigned)q[1] << 16);
      pk.y = (unsigned)q[2] | ((unsigned)q[3] << 16);
      pk.z = (unsigned)q[4] | ((unsigned)q[5] << 16);
      pk.w = (unsigned)q[6] | ((unsigned)q[7] << 16);
      *reinterpret_cast<uint4*>(&Tm[(size_t)j * N + l0 + half * 8]) = pk;
    }
  }
}

__device__ __forceinline__ void gld16(void* lds, const void* g) {
  __builtin_amdgcn_global_load_lds(
      (const __attribute__((address_space(1))) void*)g,
      (__attribute__((address_space(3))) void*)lds, 16, 0, 0);
}

// Paired triangular GEMM, K-parity wave split:
//  - Block 128x256, 8 waves. Output split 2x2 into 64x128 wave tiles (g = wave&3);
//    K-tiles split by parity (e = wave>>2): waves e=0 compute even K-tiles, e=1 odd,
//    into separate accumulators, merged via LDS at the epilogue.
//    Each SIMD hosts one wave of each parity -> MFMA pipe stays fed while the
//    SIMD-mate issues its ds_reads; only ONE barrier per 2 K-tiles.
//  - LDS traffic/MAC: reads 8*(64+128)*2/(128*256) wait-free b128 + writes
//    (128+256)*2/(128*256) = 0.070 B/MAC vs 0.094 for the 64x64-tile structure.
//  - BK=32, 6 tile buffers (144 KB), prefetch depth 2 windows: stage(w+2) issued
//    inside window w; boundary wait vmcnt(6) leaves the next 6 loads in flight.
//    Buffer residues mod 6 keep {read, landing, writing} sets disjoint.
//  - Swizzle: rows are 64 B = 4 chunks; staged chunk (row, c) holds global chunk
//    c^(row&3); reads use q = hi4^(lo16&3). Bank-group distribution is uniform.
// Grid 16 cols x 16 pairs (p, 31-p): every block runs exactly 66 windows.
__global__ __launch_bounds__(512)
void gemm_tri_kernel(const unsigned short* __restrict__ Tm,
                     const unsigned short* __restrict__ Bt,
                     const float* __restrict__ fe,
                     float* __restrict__ out) {
  __shared__ __align__(16) char sm[NBUF * TILEB];  // 144 KB

  const int tid = threadIdx.x;
  const int wave = tid >> 6, lane = tid & 63;
  const int g = wave & 3, e = wave >> 2;       // output slot / K-parity
  const int gr = g >> 1, gc = g & 1;           // 2x2 output grid of 64x128
  const int lo16 = lane & 15, hi4 = lane >> 4;
  const int qoff = (hi4 ^ (lo16 & 3)) << 4;    // read-side swizzled chunk offset
  const int i0 = blockIdx.x * BNT;
  const int p = (int)blockIdx.y;

  const size_t strideB = (size_t)N * 2;        // 8192 B per matrix row

  // staging: 512 threads cover 128 rows x 4 chunks of 16 B per pass
  const int srow = tid >> 2;                   // row within a 128-row pass
  const int gq = ((tid & 3) ^ (srow & 3)) * 16;  // pre-swizzled global chunk

  // stage K-tile t into buffer b: A (1 pass) + B (2 passes) = 3 gld16/wave
  auto stageTile = [&](int j0s, int t, int b) {
    const char* Asrc = (const char*)Tm + (size_t)(j0s + srow) * strideB + (size_t)t * 64 + gq;
    const char* Bsrc0 = (const char*)Bt + (size_t)(i0 + srow) * strideB + (size_t)t * 64 + gq;
    const char* Bsrc1 = (const char*)Bt + (size_t)(i0 + 128 + srow) * strideB + (size_t)t * 64 + gq;
    char* base = (char*)sm + b * TILEB + wave * 1024;
    gld16(base, Asrc);
    gld16(base + 8192, Bsrc0);
    gld16(base + 16384, Bsrc1);
  };

#pragma unroll 1
  for (int ph = 0; ph < 2; ++ph) {
    const int by = ph ? (31 - p) : p;
    const int j0 = by * BMT;
    const int nW = 2 * by + 2;  // windows of 2 K-tiles; total tiles = 4by+4 (K <= 128(by+1))

    f32x4 acc[4][8] = {};

    // prologue: stage windows 0 and 1 (tiles 0..3, 12 gld16/wave in flight)
    stageTile(j0, 0, 0); stageTile(j0, 1, 1);
    stageTile(j0, 2, 2); stageTile(j0, 3, 3);
    asm volatile("s_waitcnt vmcnt(6)" ::: "memory");  // window 0 landed; window 1 in flight
    __builtin_amdgcn_s_barrier();

    int bw = 0;  // buffer of tile 2w (even residues 0,2,4)
#pragma unroll 1
    for (int w = 0; w < nW; ++w) {
      const bool doStage = (w + 2 < nW);
      if (doStage) {
        const int s0 = (bw + 4 >= NBUF) ? bw - 2 : bw + 4;  // (2w+4)%6
        stageTile(j0, 2 * w + 4, s0);
        stageTile(j0, 2 * w + 5, s0 + 1);
      }
      // my K-tile this window: t = 2w + e, buffer bw + e
      const char* Ab = (const char*)sm + (bw + e) * TILEB;
      const char* Bb = Ab + 8192;
      bf16x8 af[4], bfr[8];
#pragma unroll
      for (int mt = 0; mt < 4; ++mt)
        af[mt] = *reinterpret_cast<const bf16x8*>(Ab + (gr * 64 + mt * 16 + lo16) * 64 + qoff);
#pragma unroll
      for (int nt = 0; nt < 8; ++nt)
        bfr[nt] = *reinterpret_cast<const bf16x8*>(Bb + (gc * 128 + nt * 16 + lo16) * 64 + qoff);
      __builtin_amdgcn_s_setprio(1);
#pragma unroll
      for (int mt = 0; mt < 4; ++mt)
#pragma unroll
        for (int nt = 0; nt < 8; ++nt)
          acc[mt][nt] = __builtin_amdgcn_mfma_f32_16x16x32_bf16(
              af[mt], bfr[nt], acc[mt][nt], 0, 0, 0);
      __builtin_amdgcn_s_setprio(0);
      // boundary: next window's 2 tiles must have landed; keep the 6 newest in flight
      if (doStage) {
        asm volatile("s_waitcnt vmcnt(6)" ::: "memory");
      } else {
        asm volatile("s_waitcnt vmcnt(0)" ::: "memory");
      }
      __builtin_amdgcn_s_barrier();
      bw += 2; if (bw >= NBUF) bw = 0;
    }

    // Epilogue: merge K-parities via LDS (odd writes, even adds + stores).
    if (e == 1) {
#pragma unroll
      for (int mt = 0; mt < 4; ++mt)
#pragma unroll
        for (int nt = 0; nt < 8; ++nt)
          *reinterpret_cast<f32x4*>((char*)sm + g * 32768 + (mt * 8 + nt) * 1024 + lane * 16) =
              acc[mt][nt];
    }
    __syncthreads();
    if (e == 0) {
#pragma unroll
      for (int mt = 0; mt < 4; ++mt) {
        const int jb = j0 + gr * 64 + mt * 16 + hi4 * 4;
        const float4 fev = *reinterpret_cast<const float4*>(&fe[jb]);
        const float fes[4] = {fev.x, fev.y, fev.z, fev.w};
#pragma unroll
        for (int nt = 0; nt < 8; ++nt) {
          const f32x4 o = *reinterpret_cast<const f32x4*>(
              (char*)sm + g * 32768 + (mt * 8 + nt) * 1024 + lane * 16);
          const int i = i0 + gc * 128 + nt * 16 + lo16;
#pragma unroll
          for (int r = 0; r < 4; ++r)
            out[(size_t)(jb + r) * M + i] = fmaf(-DT, acc[mt][nt][r] + o[r], fes[r]);
        }
      }
    }
    __syncthreads();  // LDS dead before next phase's staging overwrites it
  }
}

extern "C" void kernel_launch(void* const* d_in, const int* in_sizes, int n_in,
                              void* d_out, int out_size, void* d_ws, size_t ws_size,
                              hipStream_t stream) {
  const float* x  = (const float*)d_in[0];
  const float* fe = (const float*)d_in[1];
  const float* h  = (const float*)d_in[2];
  float* out = (float*)d_out;

  const size_t matBytes = (size_t)N * N * sizeof(unsigned short);  // 32 MiB
  if (ws_size < 2 * matBytes) return;

  unsigned short* kbT = (unsigned short*)d_ws;
  unsigned short* Tm  = (unsigned short*)((char*)d_ws + matBytes);

  prep_kernel<<<8192, 256, 0, stream>>>(x, h, kbT, Tm);
  gemm_tri_kernel<<<dim3(M / BNT, 16), 512, 0, stream>>>(Tm, kbT, fe, out);
}